// Round 1
// 217.856 us; speedup vs baseline: 1.0016x; 1.0016x over previous
//
#include <hip/hip_runtime.h>
#include <hip/hip_bf16.h>
#include <math.h>

#define D_MODEL 1024
#define SEQ     1024
#define BATCH   4
#define NHEADS  16
#define HD      64

// log2(e) folds: p = exp2(s') with s' = (q.k)*0.125*log2e + 0.05*log2e*vimp
// (kimp term is constant per q-row -> cancels in softmax; dropped entirely)
#define QSC 0.18033688f   // 0.125 * log2(e)
#define BSC 0.072134752f  // 0.05  * log2(e)

typedef __bf16 bf16x8 __attribute__((ext_vector_type(8)));
typedef __bf16 bf16x4 __attribute__((ext_vector_type(4)));
typedef float  f32x4  __attribute__((ext_vector_type(4)));

__device__ __forceinline__ f32x4 mfma16(bf16x8 a, bf16x8 b, f32x4 c) {
  return __builtin_amdgcn_mfma_f32_16x16x32_bf16(a, b, c, 0, 0, 0);
}

// async global->LDS, 16B per lane; LDS dest = wave-uniform base + lane*16
__device__ __forceinline__ void async16(__bf16* lds, const __bf16* g) {
  __builtin_amdgcn_global_load_lds(g, lds, 16, 0, 0);
}

// ------------------------------------------ fused prep: cvt x, cvt weights, vimp
__global__ __launch_bounds__(256) void prep_kernel(
    const float* __restrict__ x,
    const float* __restrict__ Wq, const float* __restrict__ Wk,
    const float* __restrict__ Wv, const float* __restrict__ Wo,
    const float* __restrict__ v_ema,
    const float* __restrict__ Wimp, const float* __restrict__ bimp,
    __bf16* __restrict__ x_bf, __bf16* __restrict__ wq_bf, __bf16* __restrict__ wk_bf,
    __bf16* __restrict__ wv_bf, __bf16* __restrict__ wo_bf,
    float* __restrict__ vimp) {
  const int bid = blockIdx.x;
  const int tid = threadIdx.x;
  if (bid < 4096) {                       // x: 4M floats = 1M float4
    int i = bid * 256 + tid;
    float4 v = ((const float4*)x)[i];
    bf16x4 o; o[0] = (__bf16)v.x; o[1] = (__bf16)v.y; o[2] = (__bf16)v.z; o[3] = (__bf16)v.w;
    ((bf16x4*)x_bf)[i] = o;
  } else if (bid < 8192) {                // 4 weight mats: 4 x 256K float4
    int i = (bid - 4096) * 256 + tid;
    int sel = i >> 18;
    int j = i & 262143;
    const float* s = (sel == 0) ? Wq : (sel == 1) ? Wk : (sel == 2) ? Wv : Wo;
    __bf16* d      = (sel == 0) ? wq_bf : (sel == 1) ? wk_bf : (sel == 2) ? wv_bf : wo_bf;
    float4 v = ((const float4*)s)[j];
    bf16x4 o; o[0] = (__bf16)v.x; o[1] = (__bf16)v.y; o[2] = (__bf16)v.z; o[3] = (__bf16)v.w;
    ((bf16x4*)d)[j] = o;
  } else {                                // vimp: one wave per (h,s), 16384 waves
    int gw   = (bid - 8192) * 4 + (tid >> 6);
    int lane = tid & 63;
    int h = gw >> 10, s = gw & 1023;
    float sum = 0.f;
    for (int d = lane; d < D_MODEL; d += 64)
      sum += v_ema[s * D_MODEL + d] * Wimp[h * D_MODEL + d];
    for (int mm = 32; mm >= 1; mm >>= 1) sum += __shfl_xor(sum, mm);
    if (lane == 0) vimp[h * SEQ + s] = sum + bimp[h];
  }
}

// ---------------------------------------------------- QKV: 256x256 tile, BK=64, 8-phase
// 8 waves (2M x 4N), 512 threads, 128 KiB LDS double-buffer, counted vmcnt(6)
// (never 0 in-loop), setprio around MFMA clusters, XCD-chunked block swizzle.
// z==1 (K proj): transposed product, Kp[bh][key][64] with col' = (col+(key&7)*8)&63.
// z==2 (V proj): Vp[bh][key>>6][d][64] with key' = (key+(d&7)*8)&63.
// Stage-region discipline: during tile t's phases we stage
//   q0: B rows 128-255 of tile t+1 (other buffer - consumed a full tile ago)
//   q1: A rows {0-63,128-191} of t+2 (this buffer - consumed at q0, drained)
//   q2: B rows 0-127 of t+2        (consumed at q0+q1, drained)
//   q3: A rows {64-127,192-255} of t+2 (consumed at q2, drained)
// so every DMA overwrite lands only in regions whose reads drained at a prior barrier.
// vmcnt(6) at end of q3 guarantees tile t+1 fully landed (exactly 6 newer loads).
// Tail tiles stage harmlessly past K (reads stay inside the workspace; the
// garbage lands in LDS regions never read again) to keep vmcnt accounting uniform.

#define STA(BUF, R0, KT) async16(&As[BUF][(R0) * 64 + tid8], aS + (size_t)(R0) * 1024 + (KT) * 64)
#define STB(BUF, R0, KT) async16(&Bs[BUF][(R0) * 64 + tid8], bS + (size_t)(R0) * 1024 + (KT) * 64)

#define LOAD_A(MH)                                                                      \
  _Pragma("unroll") for (int mi = 0; mi < 4; ++mi) {                                    \
    afr[mi][0] = *(const bf16x8*)&As[buf][aro + (MH) * 4096 + mi * 1024 + ph0];         \
    afr[mi][1] = *(const bf16x8*)&As[buf][aro + (MH) * 4096 + mi * 1024 + (ph0 ^ 32)];  \
  }
#define LOAD_B(BF, NH)                                                                  \
  _Pragma("unroll") for (int ni = 0; ni < 2; ++ni) {                                    \
    BF[ni][0] = *(const bf16x8*)&Bs[buf][bro + (NH) * 2048 + ni * 1024 + ph0];          \
    BF[ni][1] = *(const bf16x8*)&Bs[buf][bro + (NH) * 2048 + ni * 1024 + (ph0 ^ 32)];   \
  }

#define MFMA_QUAD(MB, NB, BF)                                                           \
  if (zk) {                                                                             \
    _Pragma("unroll") for (int mi = 0; mi < 4; ++mi)                                    \
      _Pragma("unroll") for (int ni = 0; ni < 2; ++ni) {                                \
        acc[(MB) + mi][(NB) + ni] = mfma16(BF[ni][0], afr[mi][0], acc[(MB) + mi][(NB) + ni]); \
        acc[(MB) + mi][(NB) + ni] = mfma16(BF[ni][1], afr[mi][1], acc[(MB) + mi][(NB) + ni]); \
      }                                                                                 \
  } else {                                                                              \
    _Pragma("unroll") for (int mi = 0; mi < 4; ++mi)                                    \
      _Pragma("unroll") for (int ni = 0; ni < 2; ++ni) {                                \
        acc[(MB) + mi][(NB) + ni] = mfma16(afr[mi][0], BF[ni][0], acc[(MB) + mi][(NB) + ni]); \
        acc[(MB) + mi][(NB) + ni] = mfma16(afr[mi][1], BF[ni][1], acc[(MB) + mi][(NB) + ni]); \
      }                                                                                 \
  }

#define BAR() __builtin_amdgcn_s_barrier()
#define LGKM0()                                           \
  {                                                       \
    asm volatile("s_waitcnt lgkmcnt(0)" ::: "memory");    \
    __builtin_amdgcn_sched_barrier(0);                    \
  }

__global__ __launch_bounds__(512, 2) void gemm_qkv_8p(
    const __bf16* __restrict__ A,
    const __bf16* __restrict__ W0, const __bf16* __restrict__ W1, const __bf16* __restrict__ W2,
    const float* __restrict__ b0, const float* __restrict__ b1, const float* __restrict__ b2,
    __bf16* __restrict__ q_out, __bf16* __restrict__ kp, __bf16* __restrict__ vp,
    float qsc) {
  // bijective XCD-chunked swizzle: 192 blocks, 8 XCDs x 24 contiguous
  const int id = blockIdx.x;
  const int swz = (id & 7) * 24 + (id >> 3);
  const int bx = swz & 3, by = (swz >> 2) & 15, z = swz >> 6;
  const __bf16* W   = (z == 0) ? W0 : (z == 1) ? W1 : W2;
  const float* bias = (z == 0) ? b0 : (z == 1) ? b1 : b2;
  const bool zk = (z == 1);

  __shared__ __bf16 As[2][16384];   // 256 rows x 64 k, chunk-XOR-swizzled
  __shared__ __bf16 Bs[2][16384];

  const int tid = threadIdx.x;
  const int l = tid & 63, wid = tid >> 6;
  const int quad = l >> 4, l16 = l & 15;
  const int wy = wid >> 2, wx = wid & 3;
  const int row0 = by * 256, col0 = bx * 256;

  // staging: thread covers row rk, 16B chunk ck of each 64-row call;
  // global source chunk pre-XOR'd so linear LDS holds the swizzled layout
  const int rk = tid >> 3;
  const int csw = ((tid & 7) ^ (rk & 7)) * 8;
  const int tid8 = tid * 8;
  const __bf16* aS = A + (size_t)(row0 + rk) * 1024 + csw;
  const __bf16* bS = W + (size_t)(col0 + rk) * 1024 + csw;

  // ds_read side: physical chunk = (ks*4+quad) ^ (row&7); row&7 == l16&7
  const int ph0 = (quad ^ (l16 & 7)) * 8;
  const int aro = (wy * 128 + l16) * 64;
  const int bro = (wx * 64 + l16) * 64;

  const f32x4 fzero = {0.f, 0.f, 0.f, 0.f};
  f32x4 acc[8][4];
  #pragma unroll
  for (int i = 0; i < 8; i++)
    #pragma unroll
    for (int j = 0; j < 4; j++) acc[i][j] = fzero;

  // prologue: tile0 (8 calls) + AH0(1), B01(1), AH1(1)
  STA(0, 0, 0);   STA(0, 128, 0); STA(0, 64, 0);  STA(0, 192, 0);
  STB(0, 0, 0);   STB(0, 64, 0);  STB(0, 128, 0); STB(0, 192, 0);
  STA(1, 0, 1);   STA(1, 128, 1);
  STB(1, 0, 1);   STB(1, 64, 1);
  STA(1, 64, 1);  STA(1, 192, 1);
  asm volatile("s_waitcnt vmcnt(6)" ::: "memory");   // tile0 landed
  BAR();

  #pragma unroll 2
  for (int t = 0; t < 16; ++t) {
    const int buf = t & 1, nb = buf ^ 1;
    bf16x8 afr[4][2], bfr0[2][2], bfr1[2][2];
    // ---- q0: quadrant (mh=0, nh=0)
    LOAD_A(0);
    LOAD_B(bfr0, 0);
    STB(nb, 128, t + 1); STB(nb, 192, t + 1);        // B23(t+1)
    BAR(); LGKM0();
    __builtin_amdgcn_s_setprio(1);
    MFMA_QUAD(0, 0, bfr0);
    __builtin_amdgcn_s_setprio(0);
    BAR();
    // ---- q1: (mh=0, nh=1)
    LOAD_B(bfr1, 1);
    STA(buf, 0, t + 2); STA(buf, 128, t + 2);        // AH0(t+2)
    BAR(); LGKM0();
    __builtin_amdgcn_s_setprio(1);
    MFMA_QUAD(0, 2, bfr1);
    __builtin_amdgcn_s_setprio(0);
    BAR();
    // ---- q2: (mh=1, nh=1)
    LOAD_A(1);
    STB(buf, 0, t + 2); STB(buf, 64, t + 2);         // B01(t+2)
    BAR(); LGKM0();
    __builtin_amdgcn_s_setprio(1);
    MFMA_QUAD(4, 2, bfr1);
    __builtin_amdgcn_s_setprio(0);
    BAR();
    // ---- q3: (mh=1, nh=0)  (no new ds_reads: afr mh1 + bfr0 live in regs)
    STA(buf, 64, t + 2); STA(buf, 192, t + 2);       // AH1(t+2)
    BAR();
    __builtin_amdgcn_s_setprio(1);
    MFMA_QUAD(4, 0, bfr0);
    __builtin_amdgcn_s_setprio(0);
    asm volatile("s_waitcnt vmcnt(6)" ::: "memory"); // tile t+1 fully landed
    BAR();
  }
  asm volatile("s_waitcnt vmcnt(0)" ::: "memory");   // drain tail DMA before LDS dealloc

  // ---------------- epilogue
  if (z == 1) {
    // transposed product: reg r <-> model dim, l16 <-> token; pack + rotate
    #pragma unroll
    for (int ni = 0; ni < 4; ++ni) {
      const int wcolbase = col0 + wx * 64 + ni * 16 + quad * 4;
      const float4 b4 = *(const float4*)&bias[wcolbase];
      const float bb[4] = {b4.x, b4.y, b4.z, b4.w};
      #pragma unroll
      for (int mi = 0; mi < 8; ++mi) {
        const int token = row0 + wy * 128 + mi * 16 + l16;
        const int bh = (token >> 10) * 16 + (wcolbase >> 6);
        const int colp = ((wcolbase & 63) + ((token & 7) << 3)) & 63;
        union { __bf16 hh[4]; uint2 uu; } pk;
        #pragma unroll
        for (int r = 0; r < 4; ++r) pk.hh[r] = (__bf16)(acc[mi][ni][r] + bb[r]);
        *(uint2*)(kp + ((size_t)bh * SEQ + (token & 1023)) * HD + colp) = pk.uu;
      }
    }
  } else if (z == 2) {
    #pragma unroll
    for (int ni = 0; ni < 4; ++ni) {
      const int col = col0 + wx * 64 + ni * 16 + l16;
      const float bv = bias[col];
      #pragma unroll
      for (int mi = 0; mi < 8; ++mi) {
        const int token = row0 + wy * 128 + mi * 16 + quad * 4;
        const int bh = (token >> 10) * 16 + (col >> 6);
        const int chk = (token >> 6) & 15;
        const int keyp = ((token & 63) + ((col & 7) << 3)) & 63;
        const size_t base = (((size_t)bh * 16 + chk) * 64 + (col & 63)) * 64 + keyp;
        union { __bf16 hh[4]; uint2 uu; } pk;
        #pragma unroll
        for (int r = 0; r < 4; ++r) pk.hh[r] = (__bf16)(acc[mi][ni][r] + bv);
        *(uint2*)(vp + base) = pk.uu;
      }
    }
  } else {
    #pragma unroll
    for (int ni = 0; ni < 4; ++ni) {
      const int col = col0 + wx * 64 + ni * 16 + l16;
      const float bv = bias[col];
      #pragma unroll
      for (int mi = 0; mi < 8; ++mi) {
        const int row = row0 + wy * 128 + mi * 16 + quad * 4;
        #pragma unroll
        for (int r = 0; r < 4; ++r)
          q_out[(size_t)(row + r) * D_MODEL + col] = (__bf16)((acc[mi][ni][r] + bv) * qsc);
      }
    }
  }
}

// ---------------------------------------------------- C[M,N] = (A[M,K]·W[N,K]^T + bias)*sc
// m97 structure: 128x128 tile, BK=32 — kept for the O-projection (fp32 out, 256 blocks
// fill all CUs; the 256² kernel would leave 3/4 of the chip idle at N=1024).
template<bool OUT_BF16>
__global__ __launch_bounds__(256) void gemm_bt(
    const __bf16* __restrict__ A,
    const __bf16* __restrict__ W0, const __bf16* __restrict__ W1, const __bf16* __restrict__ W2,
    const float* __restrict__ b0, const float* __restrict__ b1, const float* __restrict__ b2,
    void* out0, void* out1, void* out2, float sc0, float sc1, float sc2) {
  const int z = blockIdx.z;
  const __bf16* W   = (z == 0) ? W0 : (z == 1) ? W1 : W2;
  const float* bias = (z == 0) ? b0 : (z == 1) ? b1 : b2;
  void* out         = (z == 0) ? out0 : (z == 1) ? out1 : out2;
  const float sc    = (z == 0) ? sc0 : (z == 1) ? sc1 : sc2;

  __shared__ __bf16 As[128 * 32];
  __shared__ __bf16 Bs[128 * 32];

  const int tid = threadIdx.x;
  const int w = tid >> 6, l = tid & 63;
  const int quad = l >> 4, l16 = l & 15;
  const int wy = w >> 1, wx = w & 1;
  const int row0 = blockIdx.y * 128;
  const int col0 = blockIdx.x * 128;

  const f32x4 fzero = {0.f, 0.f, 0.f, 0.f};
  f32x4 acc[4][4];
  for (int i = 0; i < 4; i++)
    for (int j = 0; j < 4; j++) acc[i][j] = fzero;

  const int lr = l >> 2;                         // 0..15
  const int sw0 = (((l & 3) ^ (lr & 3)) * 8);    // source k offset (swizzled)
  const int rowA = w * 16 + lr;
  const __bf16* aptr = A + (size_t)(row0 + rowA) * D_MODEL + sw0;
  const __bf16* bptr = W + (size_t)(col0 + rowA) * D_MODEL + sw0;
  __bf16* lA0 = &As[w * 512 + l * 8];
  __bf16* lA1 = &As[2048 + w * 512 + l * 8];
  __bf16* lB0 = &Bs[w * 512 + l * 8];
  __bf16* lB1 = &Bs[2048 + w * 512 + l * 8];

  const int rswz = (quad ^ (l16 & 3)) * 8;

  for (int k0 = 0; k0 < D_MODEL; k0 += 32) {
    async16(lA0, aptr + k0);
    async16(lA1, aptr + (size_t)64 * D_MODEL + k0);
    async16(lB0, bptr + k0);
    async16(lB1, bptr + (size_t)64 * D_MODEL + k0);
    __syncthreads();
    bf16x8 af[4], bfr[4];
    #pragma unroll
    for (int mi = 0; mi < 4; mi++) af[mi]  = *(const bf16x8*)&As[(wy * 64 + mi * 16 + l16) * 32 + rswz];
    #pragma unroll
    for (int ni = 0; ni < 4; ni++) bfr[ni] = *(const bf16x8*)&Bs[(wx * 64 + ni * 16 + l16) * 32 + rswz];
    if (z == 1) {
      #pragma unroll
      for (int mi = 0; mi < 4; mi++)
        #pragma unroll
        for (int ni = 0; ni < 4; ni++)
          acc[mi][ni] = mfma16(bfr[ni], af[mi], acc[mi][ni]);   // transposed product
    } else {
      #pragma unroll
      for (int mi = 0; mi < 4; mi++)
        #pragma unroll
        for (int ni = 0; ni < 4; ni++)
          acc[mi][ni] = mfma16(af[mi], bfr[ni], acc[mi][ni]);
    }
    __syncthreads();
  }

  if (z == 1 && OUT_BF16) {
    // D[wcol][token]: pack 4 hd dims per uint2, rotated within the 64-dim row
    __bf16* kp = (__bf16*)out;
    #pragma unroll
    for (int ni = 0; ni < 4; ni++) {
      const int wcolbase = col0 + wx * 64 + ni * 16 + quad * 4;
      const float4 b4 = *(const float4*)&bias[wcolbase];
      const float bb[4] = {b4.x, b4.y, b4.z, b4.w};
      #pragma unroll
      for (int mi = 0; mi < 4; mi++) {
        const int token = row0 + wy * 64 + mi * 16 + l16;
        const int bh = (token >> 10) * 16 + (wcolbase >> 6);
        const int colp = ((wcolbase & 63) + ((token & 7) << 3)) & 63;   // rotation
        union { __bf16 hh[4]; uint2 uu; } pk;
        #pragma unroll
        for (int r = 0; r < 4; r++) pk.hh[r] = (__bf16)(acc[mi][ni][r] + bb[r]);
        *(uint2*)(kp + ((size_t)bh * SEQ + (token & 1023)) * HD + colp) = pk.uu;
      }
    }
  } else if (z == 2 && OUT_BF16) {
    // chunk-packed Vp[bh][token>>6][d][token'], rotated in key dim
    __bf16* vp = (__bf16*)out;
    #pragma unroll
    for (int ni = 0; ni < 4; ni++) {
      const int col = col0 + wx * 64 + ni * 16 + l16;          // d (model dim)
      const float bv = bias[col];
      #pragma unroll
      for (int mi = 0; mi < 4; mi++) {
        const int token = row0 + wy * 64 + mi * 16 + quad * 4;
        const int bh = (token >> 10) * 16 + (col >> 6);
        const int chk = (token >> 6) & 15;
        const int keyp = ((token & 63) + ((col & 7) << 3)) & 63;        // rotation
        const size_t base = (((size_t)bh * 16 + chk) * 64 + (col & 63)) * 64 + keyp;
        union { __bf16 hh[4]; uint2 uu; } pk;
        #pragma unroll
        for (int r = 0; r < 4; r++) pk.hh[r] = (__bf16)(acc[mi][ni][r] + bv);
        *(uint2*)(vp + base) = pk.uu;
      }
    }
  } else {
    #pragma unroll
    for (int ni = 0; ni < 4; ni++) {
      const int col = col0 + wx * 64 + ni * 16 + l16;
      const float bv = bias[col];
      #pragma unroll
      for (int mi = 0; mi < 4; mi++) {
        const int row = row0 + wy * 64 + mi * 16 + quad * 4;
        #pragma unroll
        for (int r = 0; r < 4; r++) {
          float v = (acc[mi][ni][r] + bv) * sc;
          if (OUT_BF16) ((__bf16*)out)[(size_t)(row + r) * D_MODEL + col] = (__bf16)v;
          else          ((float*)out)[(size_t)(row + r) * D_MODEL + col] = v;
        }
      }
    }
  }
}

// ------------------------------------------------------- attention, DMA-staged (m97-style)
// Block = 4 waves = 64 q-rows of one (bh, group). K+V chunk (16 KB) DMA'd into
// double-buffered LDS via global_load_lds; ONE barrier per chunk (drains the DMA
// issued during the previous chunk's compute -> ~free). All frag reads are
// ds_read_b128, bank-uniform thanks to the global-side row rotation.
// Snake pairing {g, 15-g}: every block runs exactly 17 chunks.
__global__ __launch_bounds__(256, 2) void attn_kernel(
    const __bf16* __restrict__ Qb, const __bf16* __restrict__ Kp,
    const __bf16* __restrict__ Vp, const float* __restrict__ vimp,
    __bf16* __restrict__ Ob) {
  const int id = blockIdx.x;
  const int bh = id & 63;                 // CU c hosts ids c, c+256 -> same bh: L2 share
  const int gg = id >> 6;                 // 0..7
  const int b = bh >> 4, h = bh & 15;
  const int tid = threadIdx.x;
  const int wave = tid >> 6, lane = tid & 63;
  const int quad = lane >> 4, l16 = lane & 15;

  __shared__ __bf16 Kl[2][4096];          // 64 keys x 64 dims (rotated rows)
  __shared__ __bf16 Vl[2][4096];          // 64 dims x 64 keys (rotated rows)
  __shared__ __bf16 Ps[4][16][72];

  const __bf16* kbase = Kp + (size_t)bh * (SEQ * HD);
  const __bf16* vbase = Vp + (size_t)bh * (SEQ * HD);
  const float* vimpH = vimp + h * SEQ;

  const int rot0 = ((quad + (l16 & 7)) & 7) * 8;        // logical cols quad*8..+7
  const int rot1 = ((quad + 4 + (l16 & 7)) & 7) * 8;    // logical cols 32+quad*8..+7
  const int frow = l16 * 64;

  #pragma unroll 1
  for (int grp = 0; grp < 2; grp++) {
    const int g = grp ? (15 - gg) : gg;
    const int nch = g + 1;
    const int qrow = g * 64 + wave * 16 + l16;
    const __bf16* qp = Qb + (size_t)(b * SEQ + qrow) * D_MODEL + h * HD;
    bf16x8 qa0 = *(const bf16x8*)(qp + quad * 8);        // Q pre-scaled by QSC in gemm
    bf16x8 qa1 = *(const bf16x8*)(qp + 32 + quad * 8);
    float l_i = 0.f;
    f32x4 o[4];
    #pragma unroll
    for (int td = 0; td < 4; td++) { o[td][0] = 0.f; o[td][1] = 0.f; o[td][2] = 0.f; o[td][3] = 0.f; }

    __syncthreads();                      // bufs free of previous group's readers
    async16(&Kl[0][tid * 8], kbase + tid * 8);
    async16(&Kl[0][2048 + tid * 8], kbase + 2048 + tid * 8);
    async16(&Vl[0][tid * 8], vbase + tid * 8);
    async16(&Vl[0][2048 + tid * 8], vbase + 2048 + tid * 8);

    for (int ch = 0; ch < nch; ch++) {
      const int buf = ch & 1;
      __syncthreads();                    // drains DMA for buf (issued ~1 chunk ago)
      if (ch + 1 < nch) {                 // prefetch next chunk into other buffer
        const __bf16* gk = kbase + (ch + 1) * 4096;
        const __bf16* gv = vbase + (ch + 1) * 4096;
        const int nb = buf ^ 1;
        async16(&Kl[nb][tid * 8], gk + tid * 8);
        async16(&Kl[nb][2048 + tid * 8], gk + 2048 + tid * 8);
        async16(&Vl[nb][tid * 8], gv + tid * 8);
        async16(&Vl[nb][2048 + tid * 8], gv + 2048 + tid * 8);
      }
      const int kc = ch * 64;
      float4 vi[4];
      #pragma unroll
      for (int t = 0; t < 4; t++) vi[t] = *(const float4*)(vimpH + kc + t * 16 + quad * 4);
      bf16x8 kf0[4], kf1[4];
      #pragma unroll
      for (int t = 0; t < 4; t++) {
        kf0[t] = *(const bf16x8*)&Kl[buf][t * 1024 + frow + rot0];
        kf1[t] = *(const bf16x8*)&Kl[buf][t * 1024 + frow + rot1];
      }
      bf16x8 vfr0[4], vfr1[4];
      #pragma unroll
      for (int td = 0; td < 4; td++) {
        vfr0[td] = *(const bf16x8*)&Vl[buf][td * 1024 + frow + rot0];
        vfr1[td] = *(const bf16x8*)&Vl[buf][td * 1024 + frow + rot1];
      }
      const f32x4 fz = {0.f, 0.f, 0.f, 0.f};
      float p[4][4];
      float lsum = 0.f;
      #pragma unroll
      for (int t = 0; t < 4; t++) {
        f32x4 sacc = fz;
        sacc = mfma16(kf0[t], qa0, sacc);
        sacc = mfma16(kf1[t], qa1, sacc);
        const float vib[4] = {vi[t].x, vi[t].y, vi[t].z, vi[t].w};
        #pragma unroll
        for (int r = 0; r < 4; r++) {
          float pp = exp2f(sacc[r] + BSC * vib[r]);
          pp = (kc + t * 16 + quad * 4 + r <= qrow) ? pp : 0.f;   // causal (full chunks pass)
          p[t][r] = pp;
          lsum += pp;
        }
      }
      l_i += lsum;
      #pragma unroll
      for (int t = 0; t < 4; t++) {
        union { __bf16 hh[4]; uint2 uu; } pk;
        #pragma unroll
        for (int r = 0; r < 4; r++) pk.hh[r] = (__bf16)p[t][r];
        *(uint2*)&Ps[wave][l16][t * 16 + quad * 4] = pk.uu;
      }
      bf16x8 pf0 = *(const bf16x8*)&Ps[wave][l16][quad * 8];
      bf16x8 pf1 = *(const bf16x8*)&Ps[wave][l16][32 + quad * 8];
      #pragma unroll
      for (int td = 0; td < 4; td++) {
        o[td] = mfma16(vfr0[td], pf0, o[td]);
        o[td] = mfma16(vfr1[td], pf1, o[td]);
      }
    }

    float L = l_i;
    L += __shfl_xor(L, 16);
    L += __shfl_xor(L, 32);
    const float il = 1.0f / L;
    __bf16* op = Ob + (size_t)(b * SEQ + qrow) * D_MODEL + h * HD;
    #pragma unroll
    for (int td = 0; td < 4; td++) {
      union { __bf16 hh[4]; uint2 uu; } pk;
      #pragma unroll
      for (int r = 0; r < 4; r++) pk.hh[r] = (__bf16)(o[td][r] * il);
      *(uint2*)(op + td * 16 + quad * 4) = pk.uu;
    }
  }
}

// ---------------------------------------------------------------------------
extern "C" void kernel_launch(void* const* d_in, const int* in_sizes, int n_in,
                              void* d_out, int out_size, void* d_ws, size_t ws_size,
                              hipStream_t stream) {
  const float* x     = (const float*)d_in[0];
  const float* Wq    = (const float*)d_in[1];
  const float* bq    = (const float*)d_in[2];
  const float* Wk    = (const float*)d_in[3];
  const float* bk    = (const float*)d_in[4];
  const float* Wv    = (const float*)d_in[5];
  const float* bv    = (const float*)d_in[6];
  const float* Wo    = (const float*)d_in[7];
  const float* bo    = (const float*)d_in[8];
  const float* Wimp  = (const float*)d_in[9];
  const float* bimp  = (const float*)d_in[10];
  // d_in[11] = k_ema (unused: kimp bias is per-q-row constant, cancels in softmax)
  const float* v_ema = (const float*)d_in[12];
  float* out = (float*)d_out;

  char* ws = (char*)d_ws;
  __bf16* x_bf  = (__bf16*)(ws);                        // 8 MB
  __bf16* wq_bf = (__bf16*)(ws + (8ull  << 20));        // 2 MB each
  __bf16* wk_bf = (__bf16*)(ws + (10ull << 20));
  __bf16* wv_bf = (__bf16*)(ws + (12ull << 20));
  __bf16* wo_bf = (__bf16*)(ws + (14ull << 20));
  __bf16* q_bf  = (__bf16*)(ws + (16ull << 20));        // 8 MB each
  __bf16* kp_bf = (__bf16*)(ws + (24ull << 20));        // K packed+rotated [bh][key][64]
  __bf16* vp_bf = (__bf16*)(ws + (32ull << 20));        // V packed+rotated [bh][ch][d][64]
  __bf16* a_bf  = (__bf16*)(ws + (40ull << 20));
  float*  vimp  = (float*)(ws + (48ull << 20));         // 64 KB

  prep_kernel<<<12288, 256, 0, stream>>>(
      x, Wq, Wk, Wv, Wo, v_ema, Wimp, bimp,
      x_bf, wq_bf, wk_bf, wv_bf, wo_bf, vimp);

  // Q,K,V projections; 256² 8-phase pipelined kernel (192 blocks, 8 waves each).
  // Q pre-scaled by 0.125*log2(e); K,V written per-head packed+rotated.
  gemm_qkv_8p<<<192, 512, 0, stream>>>(
      x_bf, wq_bf, wk_bf, wv_bf, bq, bk, bv,
      q_bf, kp_bf, vp_bf, QSC);

  attn_kernel<<<dim3(512), 256, 0, stream>>>(
      q_bf, kp_bf, vp_bf, vimp, a_bf);

  gemm_bt<false><<<dim3(8, 32, 1), 256, 0, stream>>>(
      a_bf, wo_bf, wo_bf, wo_bf, bo, bo, bo,
      (void*)out, (void*)out, (void*)out, 1.0f, 1.0f, 1.0f);
}

// Round 2
// 210.804 us; speedup vs baseline: 1.0351x; 1.0335x over previous
//
#include <hip/hip_runtime.h>
#include <hip/hip_bf16.h>
#include <math.h>

#define D_MODEL 1024
#define SEQ     1024
#define BATCH   4
#define NHEADS  16
#define HD      64

// log2(e) folds: p = exp2(s') with s' = (q.k)*0.125*log2e + 0.05*log2e*vimp
// (kimp term is constant per q-row -> cancels in softmax; dropped entirely)
#define QSC 0.18033688f   // 0.125 * log2(e)
#define BSC 0.072134752f  // 0.05  * log2(e)

typedef __bf16 bf16x8 __attribute__((ext_vector_type(8)));
typedef __bf16 bf16x4 __attribute__((ext_vector_type(4)));
typedef float  f32x4  __attribute__((ext_vector_type(4)));

__device__ __forceinline__ f32x4 mfma16(bf16x8 a, bf16x8 b, f32x4 c) {
  return __builtin_amdgcn_mfma_f32_16x16x32_bf16(a, b, c, 0, 0, 0);
}

// async global->LDS, 16B per lane; LDS dest = wave-uniform base + lane*16
__device__ __forceinline__ void async16(__bf16* lds, const __bf16* g) {
  __builtin_amdgcn_global_load_lds(g, lds, 16, 0, 0);
}

// ------------------------------------------ fused prep: cvt x, cvt weights, vimp
// vimp: ONE pass over v_ema (wave per s-row, all 16 heads accumulated in-reg)
// instead of 16 passes (h,s)-wave -> ~128MB of re-reads collapses to 4MB + L1 Wimp.
__global__ __launch_bounds__(256) void prep_kernel(
    const float* __restrict__ x,
    const float* __restrict__ Wq, const float* __restrict__ Wk,
    const float* __restrict__ Wv, const float* __restrict__ Wo,
    const float* __restrict__ v_ema,
    const float* __restrict__ Wimp, const float* __restrict__ bimp,
    __bf16* __restrict__ x_bf, __bf16* __restrict__ wq_bf, __bf16* __restrict__ wk_bf,
    __bf16* __restrict__ wv_bf, __bf16* __restrict__ wo_bf,
    float* __restrict__ vimp) {
  const int bid = blockIdx.x;
  const int tid = threadIdx.x;
  if (bid < 4096) {                       // x: 4M floats = 1M float4
    int i = bid * 256 + tid;
    float4 v = ((const float4*)x)[i];
    bf16x4 o; o[0] = (__bf16)v.x; o[1] = (__bf16)v.y; o[2] = (__bf16)v.z; o[3] = (__bf16)v.w;
    ((bf16x4*)x_bf)[i] = o;
  } else if (bid < 8192) {                // 4 weight mats: 4 x 256K float4
    int i = (bid - 4096) * 256 + tid;
    int sel = i >> 18;
    int j = i & 262143;
    const float* s = (sel == 0) ? Wq : (sel == 1) ? Wk : (sel == 2) ? Wv : Wo;
    __bf16* d      = (sel == 0) ? wq_bf : (sel == 1) ? wk_bf : (sel == 2) ? wv_bf : wo_bf;
    float4 v = ((const float4*)s)[j];
    bf16x4 o; o[0] = (__bf16)v.x; o[1] = (__bf16)v.y; o[2] = (__bf16)v.z; o[3] = (__bf16)v.w;
    ((bf16x4*)d)[j] = o;
  } else {                                // vimp: one wave per s, all 16 heads
    const int s    = (bid - 8192) * 4 + (tid >> 6);
    const int lane = tid & 63;
    const float4* ve = (const float4*)(v_ema + (size_t)s * D_MODEL);
    float acc0 = 0.f, acc1 = 0.f, acc2 = 0.f, acc3 = 0.f;
    float acc4 = 0.f, acc5 = 0.f, acc6 = 0.f, acc7 = 0.f;
    float acc8 = 0.f, acc9 = 0.f, accA = 0.f, accB = 0.f;
    float accC = 0.f, accD = 0.f, accE = 0.f, accF = 0.f;
    #pragma unroll
    for (int i = 0; i < 4; i++) {
      const int c = lane + i * 64;                 // float4 index within the row
      float4 v = ve[c];
      #define VIMP_H(H, ACC)                                                     \
        {                                                                        \
          float4 w = ((const float4*)(Wimp + (H) * D_MODEL))[c];                 \
          ACC += v.x * w.x + v.y * w.y + v.z * w.z + v.w * w.w;                  \
        }
      VIMP_H(0, acc0)  VIMP_H(1, acc1)  VIMP_H(2, acc2)  VIMP_H(3, acc3)
      VIMP_H(4, acc4)  VIMP_H(5, acc5)  VIMP_H(6, acc6)  VIMP_H(7, acc7)
      VIMP_H(8, acc8)  VIMP_H(9, acc9)  VIMP_H(10, accA) VIMP_H(11, accB)
      VIMP_H(12, accC) VIMP_H(13, accD) VIMP_H(14, accE) VIMP_H(15, accF)
      #undef VIMP_H
    }
    #define VIMP_RED(ACC)                                                        \
      for (int mm = 32; mm >= 1; mm >>= 1) ACC += __shfl_xor(ACC, mm);
    VIMP_RED(acc0) VIMP_RED(acc1) VIMP_RED(acc2) VIMP_RED(acc3)
    VIMP_RED(acc4) VIMP_RED(acc5) VIMP_RED(acc6) VIMP_RED(acc7)
    VIMP_RED(acc8) VIMP_RED(acc9) VIMP_RED(accA) VIMP_RED(accB)
    VIMP_RED(accC) VIMP_RED(accD) VIMP_RED(accE) VIMP_RED(accF)
    #undef VIMP_RED
    if (lane == 0) {
      vimp[0  * SEQ + s] = acc0 + bimp[0];  vimp[1  * SEQ + s] = acc1 + bimp[1];
      vimp[2  * SEQ + s] = acc2 + bimp[2];  vimp[3  * SEQ + s] = acc3 + bimp[3];
      vimp[4  * SEQ + s] = acc4 + bimp[4];  vimp[5  * SEQ + s] = acc5 + bimp[5];
      vimp[6  * SEQ + s] = acc6 + bimp[6];  vimp[7  * SEQ + s] = acc7 + bimp[7];
      vimp[8  * SEQ + s] = acc8 + bimp[8];  vimp[9  * SEQ + s] = acc9 + bimp[9];
      vimp[10 * SEQ + s] = accA + bimp[10]; vimp[11 * SEQ + s] = accB + bimp[11];
      vimp[12 * SEQ + s] = accC + bimp[12]; vimp[13 * SEQ + s] = accD + bimp[13];
      vimp[14 * SEQ + s] = accE + bimp[14]; vimp[15 * SEQ + s] = accF + bimp[15];
    }
  }
}

// ---------------------------------------------------- C[M,N] = (A[M,K]·W[N,K]^T + bias)*sc
// m97 structure + counted-vmcnt 2-phase: 128x128 tile, BK=32, DOUBLE-buffered LDS.
// Per K-step: issue stage(t+1) into other buffer FIRST, then s_waitcnt vmcnt(4)
// (waits only tile t's 4 DMAs, issued one full iteration earlier -> latency hidden
// under the previous step's compute), raw s_barrier (no compiler vmcnt(0) drain).
// Distance-1 hazard: stage(t+1) into buffer b is issued after the iter-t trailing
// barrier; every wave's ds_reads of b completed before that barrier (their MFMAs
// consumed them). 32KB LDS -> still 3 blocks/CU at 768-block QKV launch.
// z==1 (K proj): TRANSPOSED product, writes Kp[bh][key][64] with row-rotation
//                col' = (col + (key&7)*8) & 63 (bank-uniform b128 LDS reads in attn).
// z==2 (V proj): writes Vp[bh][key>>6][d][64] with key' = (key + (d&7)*8) & 63.
template<bool OUT_BF16>
__global__ __launch_bounds__(256) void gemm_bt(
    const __bf16* __restrict__ A,
    const __bf16* __restrict__ W0, const __bf16* __restrict__ W1, const __bf16* __restrict__ W2,
    const float* __restrict__ b0, const float* __restrict__ b1, const float* __restrict__ b2,
    void* out0, void* out1, void* out2, float sc0, float sc1, float sc2) {
  const int z = blockIdx.z;
  const __bf16* W   = (z == 0) ? W0 : (z == 1) ? W1 : W2;
  const float* bias = (z == 0) ? b0 : (z == 1) ? b1 : b2;
  void* out         = (z == 0) ? out0 : (z == 1) ? out1 : out2;
  const float sc    = (z == 0) ? sc0 : (z == 1) ? sc1 : sc2;

  __shared__ __bf16 As[2][128 * 32];
  __shared__ __bf16 Bs[2][128 * 32];

  const int tid = threadIdx.x;
  const int w = tid >> 6, l = tid & 63;
  const int quad = l >> 4, l16 = l & 15;
  const int wy = w >> 1, wx = w & 1;
  const int row0 = blockIdx.y * 128;
  const int col0 = blockIdx.x * 128;

  const f32x4 fzero = {0.f, 0.f, 0.f, 0.f};
  f32x4 acc[4][4];
  for (int i = 0; i < 4; i++)
    for (int j = 0; j < 4; j++) acc[i][j] = fzero;

  const int lr = l >> 2;                         // 0..15
  const int sw0 = (((l & 3) ^ (lr & 3)) * 8);    // source k offset (swizzled)
  const int rowA = w * 16 + lr;
  const __bf16* aptr = A + (size_t)(row0 + rowA) * D_MODEL + sw0;
  const __bf16* bptr = W + (size_t)(col0 + rowA) * D_MODEL + sw0;
  const int ldsOff = w * 512 + l * 8;

  const int rswz = (quad ^ (l16 & 3)) * 8;

  // prologue: stage K-step 0 into buffer 0
  async16(&As[0][ldsOff], aptr);
  async16(&As[0][2048 + ldsOff], aptr + (size_t)64 * D_MODEL);
  async16(&Bs[0][ldsOff], bptr);
  async16(&Bs[0][2048 + ldsOff], bptr + (size_t)64 * D_MODEL);

  #pragma unroll 2
  for (int t = 0; t < 32; ++t) {
    const int buf = t & 1;
    if (t + 1 < 32) {                            // stage next step, then counted wait
      const int nb = buf ^ 1;
      const int k1 = (t + 1) * 32;
      async16(&As[nb][ldsOff], aptr + k1);
      async16(&As[nb][2048 + ldsOff], aptr + (size_t)64 * D_MODEL + k1);
      async16(&Bs[nb][ldsOff], bptr + k1);
      async16(&Bs[nb][2048 + ldsOff], bptr + (size_t)64 * D_MODEL + k1);
      asm volatile("s_waitcnt vmcnt(4)" ::: "memory");   // tile t landed; t+1 in flight
    } else {
      asm volatile("s_waitcnt vmcnt(0)" ::: "memory");   // last tile: full drain
    }
    __builtin_amdgcn_s_barrier();
    bf16x8 af[4], bfr[4];
    #pragma unroll
    for (int mi = 0; mi < 4; mi++) af[mi]  = *(const bf16x8*)&As[buf][(wy * 64 + mi * 16 + l16) * 32 + rswz];
    #pragma unroll
    for (int ni = 0; ni < 4; ni++) bfr[ni] = *(const bf16x8*)&Bs[buf][(wx * 64 + ni * 16 + l16) * 32 + rswz];
    if (z == 1) {
      #pragma unroll
      for (int mi = 0; mi < 4; mi++)
        #pragma unroll
        for (int ni = 0; ni < 4; ni++)
          acc[mi][ni] = mfma16(bfr[ni], af[mi], acc[mi][ni]);   // transposed product
    } else {
      #pragma unroll
      for (int mi = 0; mi < 4; mi++)
        #pragma unroll
        for (int ni = 0; ni < 4; ni++)
          acc[mi][ni] = mfma16(af[mi], bfr[ni], acc[mi][ni]);
    }
    __builtin_amdgcn_s_barrier();
  }

  if (z == 1 && OUT_BF16) {
    // D[wcol][token]: pack 4 hd dims per uint2, rotated within the 64-dim row
    __bf16* kp = (__bf16*)out;
    #pragma unroll
    for (int ni = 0; ni < 4; ni++) {
      const int wcolbase = col0 + wx * 64 + ni * 16 + quad * 4;
      const float4 b4 = *(const float4*)&bias[wcolbase];
      const float bb[4] = {b4.x, b4.y, b4.z, b4.w};
      #pragma unroll
      for (int mi = 0; mi < 4; mi++) {
        const int token = row0 + wy * 64 + mi * 16 + l16;
        const int bh = (token >> 10) * 16 + (wcolbase >> 6);
        const int colp = ((wcolbase & 63) + ((token & 7) << 3)) & 63;   // rotation
        union { __bf16 hh[4]; uint2 uu; } pk;
        #pragma unroll
        for (int r = 0; r < 4; r++) pk.hh[r] = (__bf16)(acc[mi][ni][r] + bb[r]);
        *(uint2*)(kp + ((size_t)bh * SEQ + (token & 1023)) * HD + colp) = pk.uu;
      }
    }
  } else if (z == 2 && OUT_BF16) {
    // chunk-packed Vp[bh][token>>6][d][token'], rotated in key dim
    __bf16* vp = (__bf16*)out;
    #pragma unroll
    for (int ni = 0; ni < 4; ni++) {
      const int col = col0 + wx * 64 + ni * 16 + l16;          // d (model dim)
      const float bv = bias[col];
      #pragma unroll
      for (int mi = 0; mi < 4; mi++) {
        const int token = row0 + wy * 64 + mi * 16 + quad * 4;
        const int bh = (token >> 10) * 16 + (col >> 6);
        const int chk = (token >> 6) & 15;
        const int keyp = ((token & 63) + ((col & 7) << 3)) & 63;        // rotation
        const size_t base = (((size_t)bh * 16 + chk) * 64 + (col & 63)) * 64 + keyp;
        union { __bf16 hh[4]; uint2 uu; } pk;
        #pragma unroll
        for (int r = 0; r < 4; r++) pk.hh[r] = (__bf16)(acc[mi][ni][r] + bv);
        *(uint2*)(vp + base) = pk.uu;
      }
    }
  } else {
    #pragma unroll
    for (int ni = 0; ni < 4; ni++) {
      const int col = col0 + wx * 64 + ni * 16 + l16;
      const float bv = bias[col];
      #pragma unroll
      for (int mi = 0; mi < 4; mi++) {
        const int row = row0 + wy * 64 + mi * 16 + quad * 4;
        #pragma unroll
        for (int r = 0; r < 4; r++) {
          float v = (acc[mi][ni][r] + bv) * sc;
          if (OUT_BF16) ((__bf16*)out)[(size_t)(row + r) * D_MODEL + col] = (__bf16)v;
          else          ((float*)out)[(size_t)(row + r) * D_MODEL + col] = v;
        }
      }
    }
  }
}

// ------------------------------------------------------- attention, DMA-staged (m97-style)
// Block = 4 waves = 64 q-rows of one (bh, group). K+V chunk (16 KB) DMA'd into
// double-buffered LDS via global_load_lds; ONE barrier per chunk (drains the DMA
// issued during the previous chunk's compute -> ~free). All frag reads are
// ds_read_b128, bank-uniform thanks to the global-side row rotation.
// Snake pairing {g, 15-g}: every block runs exactly 17 chunks.
// Causal mask applies ONLY to the diagonal chunk (ch == nch-1): for ch < g,
// kc+63 <= g*64 <= qrow always -> mask hoisted behind a uniform branch.
__global__ __launch_bounds__(256, 2) void attn_kernel(
    const __bf16* __restrict__ Qb, const __bf16* __restrict__ Kp,
    const __bf16* __restrict__ Vp, const float* __restrict__ vimp,
    __bf16* __restrict__ Ob) {
  const int id = blockIdx.x;
  const int bh = id & 63;                 // CU c hosts ids c, c+256 -> same bh: L2 share
  const int gg = id >> 6;                 // 0..7
  const int b = bh >> 4, h = bh & 15;
  const int tid = threadIdx.x;
  const int wave = tid >> 6, lane = tid & 63;
  const int quad = lane >> 4, l16 = lane & 15;

  __shared__ __bf16 Kl[2][4096];          // 64 keys x 64 dims (rotated rows)
  __shared__ __bf16 Vl[2][4096];          // 64 dims x 64 keys (rotated rows)
  __shared__ __bf16 Ps[4][16][72];

  const __bf16* kbase = Kp + (size_t)bh * (SEQ * HD);
  const __bf16* vbase = Vp + (size_t)bh * (SEQ * HD);
  const float* vimpH = vimp + h * SEQ;

  const int rot0 = ((quad + (l16 & 7)) & 7) * 8;        // logical cols quad*8..+7
  const int rot1 = ((quad + 4 + (l16 & 7)) & 7) * 8;    // logical cols 32+quad*8..+7
  const int frow = l16 * 64;

  #pragma unroll 1
  for (int grp = 0; grp < 2; grp++) {
    const int g = grp ? (15 - gg) : gg;
    const int nch = g + 1;
    const int qrow = g * 64 + wave * 16 + l16;
    const __bf16* qp = Qb + (size_t)(b * SEQ + qrow) * D_MODEL + h * HD;
    bf16x8 qa0 = *(const bf16x8*)(qp + quad * 8);        // Q pre-scaled by QSC in gemm
    bf16x8 qa1 = *(const bf16x8*)(qp + 32 + quad * 8);
    float l_i = 0.f;
    f32x4 o[4];
    #pragma unroll
    for (int td = 0; td < 4; td++) { o[td][0] = 0.f; o[td][1] = 0.f; o[td][2] = 0.f; o[td][3] = 0.f; }

    __syncthreads();                      // bufs free of previous group's readers
    async16(&Kl[0][tid * 8], kbase + tid * 8);
    async16(&Kl[0][2048 + tid * 8], kbase + 2048 + tid * 8);
    async16(&Vl[0][tid * 8], vbase + tid * 8);
    async16(&Vl[0][2048 + tid * 8], vbase + 2048 + tid * 8);

    for (int ch = 0; ch < nch; ch++) {
      const int buf = ch & 1;
      __syncthreads();                    // drains DMA for buf (issued ~1 chunk ago)
      if (ch + 1 < nch) {                 // prefetch next chunk into other buffer
        const __bf16* gk = kbase + (ch + 1) * 4096;
        const __bf16* gv = vbase + (ch + 1) * 4096;
        const int nb = buf ^ 1;
        async16(&Kl[nb][tid * 8], gk + tid * 8);
        async16(&Kl[nb][2048 + tid * 8], gk + 2048 + tid * 8);
        async16(&Vl[nb][tid * 8], gv + tid * 8);
        async16(&Vl[nb][2048 + tid * 8], gv + 2048 + tid * 8);
      }
      const int kc = ch * 64;
      float4 vi[4];
      #pragma unroll
      for (int t = 0; t < 4; t++) vi[t] = *(const float4*)(vimpH + kc + t * 16 + quad * 4);
      bf16x8 kf0[4], kf1[4];
      #pragma unroll
      for (int t = 0; t < 4; t++) {
        kf0[t] = *(const bf16x8*)&Kl[buf][t * 1024 + frow + rot0];
        kf1[t] = *(const bf16x8*)&Kl[buf][t * 1024 + frow + rot1];
      }
      bf16x8 vfr0[4], vfr1[4];
      #pragma unroll
      for (int td = 0; td < 4; td++) {
        vfr0[td] = *(const bf16x8*)&Vl[buf][td * 1024 + frow + rot0];
        vfr1[td] = *(const bf16x8*)&Vl[buf][td * 1024 + frow + rot1];
      }
      const f32x4 fz = {0.f, 0.f, 0.f, 0.f};
      float p[4][4];
      float lsum = 0.f;
      if (ch == nch - 1) {                // diagonal chunk: causal mask active
        #pragma unroll
        for (int t = 0; t < 4; t++) {
          f32x4 sacc = fz;
          sacc = mfma16(kf0[t], qa0, sacc);
          sacc = mfma16(kf1[t], qa1, sacc);
          const float vib[4] = {vi[t].x, vi[t].y, vi[t].z, vi[t].w};
          #pragma unroll
          for (int r = 0; r < 4; r++) {
            float pp = exp2f(sacc[r] + BSC * vib[r]);
            pp = (kc + t * 16 + quad * 4 + r <= qrow) ? pp : 0.f;
            p[t][r] = pp;
            lsum += pp;
          }
        }
      } else {                            // interior chunk: all keys <= qrow
        #pragma unroll
        for (int t = 0; t < 4; t++) {
          f32x4 sacc = fz;
          sacc = mfma16(kf0[t], qa0, sacc);
          sacc = mfma16(kf1[t], qa1, sacc);
          const float vib[4] = {vi[t].x, vi[t].y, vi[t].z, vi[t].w};
          #pragma unroll
          for (int r = 0; r < 4; r++) {
            float pp = exp2f(sacc[r] + BSC * vib[r]);
            p[t][r] = pp;
            lsum += pp;
          }
        }
      }
      l_i += lsum;
      #pragma unroll
      for (int t = 0; t < 4; t++) {
        union { __bf16 hh[4]; uint2 uu; } pk;
        #pragma unroll
        for (int r = 0; r < 4; r++) pk.hh[r] = (__bf16)p[t][r];
        *(uint2*)&Ps[wave][l16][t * 16 + quad * 4] = pk.uu;
      }
      bf16x8 pf0 = *(const bf16x8*)&Ps[wave][l16][quad * 8];
      bf16x8 pf1 = *(const bf16x8*)&Ps[wave][l16][32 + quad * 8];
      #pragma unroll
      for (int td = 0; td < 4; td++) {
        o[td] = mfma16(vfr0[td], pf0, o[td]);
        o[td] = mfma16(vfr1[td], pf1, o[td]);
      }
    }

    float L = l_i;
    L += __shfl_xor(L, 16);
    L += __shfl_xor(L, 32);
    const float il = 1.0f / L;
    __bf16* op = Ob + (size_t)(b * SEQ + qrow) * D_MODEL + h * HD;
    #pragma unroll
    for (int td = 0; td < 4; td++) {
      union { __bf16 hh[4]; uint2 uu; } pk;
      #pragma unroll
      for (int r = 0; r < 4; r++) pk.hh[r] = (__bf16)(o[td][r] * il);
      *(uint2*)(op + td * 16 + quad * 4) = pk.uu;
    }
  }
}

// ---------------------------------------------------------------------------
extern "C" void kernel_launch(void* const* d_in, const int* in_sizes, int n_in,
                              void* d_out, int out_size, void* d_ws, size_t ws_size,
                              hipStream_t stream) {
  const float* x     = (const float*)d_in[0];
  const float* Wq    = (const float*)d_in[1];
  const float* bq    = (const float*)d_in[2];
  const float* Wk    = (const float*)d_in[3];
  const float* bk    = (const float*)d_in[4];
  const float* Wv    = (const float*)d_in[5];
  const float* bv    = (const float*)d_in[6];
  const float* Wo    = (const float*)d_in[7];
  const float* bo    = (const float*)d_in[8];
  const float* Wimp  = (const float*)d_in[9];
  const float* bimp  = (const float*)d_in[10];
  // d_in[11] = k_ema (unused: kimp bias is per-q-row constant, cancels in softmax)
  const float* v_ema = (const float*)d_in[12];
  float* out = (float*)d_out;

  char* ws = (char*)d_ws;
  __bf16* x_bf  = (__bf16*)(ws);                        // 8 MB
  __bf16* wq_bf = (__bf16*)(ws + (8ull  << 20));        // 2 MB each
  __bf16* wk_bf = (__bf16*)(ws + (10ull << 20));
  __bf16* wv_bf = (__bf16*)(ws + (12ull << 20));
  __bf16* wo_bf = (__bf16*)(ws + (14ull << 20));
  __bf16* q_bf  = (__bf16*)(ws + (16ull << 20));        // 8 MB each
  __bf16* kp_bf = (__bf16*)(ws + (24ull << 20));        // K packed+rotated [bh][key][64]
  __bf16* vp_bf = (__bf16*)(ws + (32ull << 20));        // V packed+rotated [bh][ch][d][64]
  __bf16* a_bf  = (__bf16*)(ws + (40ull << 20));
  float*  vimp  = (float*)(ws + (48ull << 20));         // 64 KB

  prep_kernel<<<8448, 256, 0, stream>>>(
      x, Wq, Wk, Wv, Wo, v_ema, Wimp, bimp,
      x_bf, wq_bf, wk_bf, wv_bf, wo_bf, vimp);

  // Q,K,V projections; Q pre-scaled by 0.125*log2(e); K,V written per-head packed+rotated
  gemm_bt<true><<<dim3(8, 32, 3), 256, 0, stream>>>(
      x_bf, wq_bf, wk_bf, wv_bf, bq, bk, bv,
      (void*)q_bf, (void*)kp_bf, (void*)vp_bf, QSC, 1.0f, 1.0f);

  attn_kernel<<<dim3(512), 256, 0, stream>>>(
      q_bf, kp_bf, vp_bf, vimp, a_bf);

  gemm_bt<false><<<dim3(8, 32, 1), 256, 0, stream>>>(
      a_bf, wo_bf, wo_bf, wo_bf, bo, bo, bo,
      (void*)out, (void*)out, (void*)out, 1.0f, 1.0f, 1.0f);
}

// Round 3
// 208.690 us; speedup vs baseline: 1.0456x; 1.0101x over previous
//
#include <hip/hip_runtime.h>
#include <hip/hip_bf16.h>
#include <math.h>

#define D_MODEL 1024
#define SEQ     1024
#define BATCH   4
#define NHEADS  16
#define HD      64

// log2(e) folds: p = exp2(s') with s' = (q.k)*0.125*log2e + 0.05*log2e*vimp
// (kimp term is constant per q-row -> cancels in softmax; dropped entirely)
#define QSC 0.18033688f   // 0.125 * log2(e)
#define BSC 0.072134752f  // 0.05  * log2(e)

typedef __bf16 bf16x8 __attribute__((ext_vector_type(8)));
typedef __bf16 bf16x4 __attribute__((ext_vector_type(4)));
typedef float  f32x4  __attribute__((ext_vector_type(4)));

__device__ __forceinline__ f32x4 mfma16(bf16x8 a, bf16x8 b, f32x4 c) {
  return __builtin_amdgcn_mfma_f32_16x16x32_bf16(a, b, c, 0, 0, 0);
}

// async global->LDS, 16B per lane; LDS dest = wave-uniform base + lane*16
__device__ __forceinline__ void async16(__bf16* lds, const __bf16* g) {
  __builtin_amdgcn_global_load_lds(g, lds, 16, 0, 0);
}

// ------------------------------------------ fused prep: cvt x, cvt weights, vimp
// vimp: ONE pass over v_ema (wave per s-row, all 16 heads accumulated in-reg).
__global__ __launch_bounds__(256) void prep_kernel(
    const float* __restrict__ x,
    const float* __restrict__ Wq, const float* __restrict__ Wk,
    const float* __restrict__ Wv, const float* __restrict__ Wo,
    const float* __restrict__ v_ema,
    const float* __restrict__ Wimp, const float* __restrict__ bimp,
    __bf16* __restrict__ x_bf, __bf16* __restrict__ wq_bf, __bf16* __restrict__ wk_bf,
    __bf16* __restrict__ wv_bf, __bf16* __restrict__ wo_bf,
    float* __restrict__ vimp) {
  const int bid = blockIdx.x;
  const int tid = threadIdx.x;
  if (bid < 4096) {                       // x: 4M floats = 1M float4
    int i = bid * 256 + tid;
    float4 v = ((const float4*)x)[i];
    bf16x4 o; o[0] = (__bf16)v.x; o[1] = (__bf16)v.y; o[2] = (__bf16)v.z; o[3] = (__bf16)v.w;
    ((bf16x4*)x_bf)[i] = o;
  } else if (bid < 8192) {                // 4 weight mats: 4 x 256K float4
    int i = (bid - 4096) * 256 + tid;
    int sel = i >> 18;
    int j = i & 262143;
    const float* s = (sel == 0) ? Wq : (sel == 1) ? Wk : (sel == 2) ? Wv : Wo;
    __bf16* d      = (sel == 0) ? wq_bf : (sel == 1) ? wk_bf : (sel == 2) ? wv_bf : wo_bf;
    float4 v = ((const float4*)s)[j];
    bf16x4 o; o[0] = (__bf16)v.x; o[1] = (__bf16)v.y; o[2] = (__bf16)v.z; o[3] = (__bf16)v.w;
    ((bf16x4*)d)[j] = o;
  } else {                                // vimp: one wave per s, all 16 heads
    const int s    = (bid - 8192) * 4 + (tid >> 6);
    const int lane = tid & 63;
    const float4* ve = (const float4*)(v_ema + (size_t)s * D_MODEL);
    float acc0 = 0.f, acc1 = 0.f, acc2 = 0.f, acc3 = 0.f;
    float acc4 = 0.f, acc5 = 0.f, acc6 = 0.f, acc7 = 0.f;
    float acc8 = 0.f, acc9 = 0.f, accA = 0.f, accB = 0.f;
    float accC = 0.f, accD = 0.f, accE = 0.f, accF = 0.f;
    #pragma unroll
    for (int i = 0; i < 4; i++) {
      const int c = lane + i * 64;                 // float4 index within the row
      float4 v = ve[c];
      #define VIMP_H(H, ACC)                                                     \
        {                                                                        \
          float4 w = ((const float4*)(Wimp + (H) * D_MODEL))[c];                 \
          ACC += v.x * w.x + v.y * w.y + v.z * w.z + v.w * w.w;                  \
        }
      VIMP_H(0, acc0)  VIMP_H(1, acc1)  VIMP_H(2, acc2)  VIMP_H(3, acc3)
      VIMP_H(4, acc4)  VIMP_H(5, acc5)  VIMP_H(6, acc6)  VIMP_H(7, acc7)
      VIMP_H(8, acc8)  VIMP_H(9, acc9)  VIMP_H(10, accA) VIMP_H(11, accB)
      VIMP_H(12, accC) VIMP_H(13, accD) VIMP_H(14, accE) VIMP_H(15, accF)
      #undef VIMP_H
    }
    #define VIMP_RED(ACC)                                                        \
      for (int mm = 32; mm >= 1; mm >>= 1) ACC += __shfl_xor(ACC, mm);
    VIMP_RED(acc0) VIMP_RED(acc1) VIMP_RED(acc2) VIMP_RED(acc3)
    VIMP_RED(acc4) VIMP_RED(acc5) VIMP_RED(acc6) VIMP_RED(acc7)
    VIMP_RED(acc8) VIMP_RED(acc9) VIMP_RED(accA) VIMP_RED(accB)
    VIMP_RED(accC) VIMP_RED(accD) VIMP_RED(accE) VIMP_RED(accF)
    #undef VIMP_RED
    if (lane == 0) {
      vimp[0  * SEQ + s] = acc0 + bimp[0];  vimp[1  * SEQ + s] = acc1 + bimp[1];
      vimp[2  * SEQ + s] = acc2 + bimp[2];  vimp[3  * SEQ + s] = acc3 + bimp[3];
      vimp[4  * SEQ + s] = acc4 + bimp[4];  vimp[5  * SEQ + s] = acc5 + bimp[5];
      vimp[6  * SEQ + s] = acc6 + bimp[6];  vimp[7  * SEQ + s] = acc7 + bimp[7];
      vimp[8  * SEQ + s] = acc8 + bimp[8];  vimp[9  * SEQ + s] = acc9 + bimp[9];
      vimp[10 * SEQ + s] = accA + bimp[10]; vimp[11 * SEQ + s] = accB + bimp[11];
      vimp[12 * SEQ + s] = accC + bimp[12]; vimp[13 * SEQ + s] = accD + bimp[13];
      vimp[14 * SEQ + s] = accE + bimp[14]; vimp[15 * SEQ + s] = accF + bimp[15];
    }
  }
}

// ---------------------------------------------------- C[M,N] = (A[M,K]·W[N,K]^T + bias)*sc
// m97 structure + QUAD-buffered LDS, prefetch distance 3, counted vmcnt(12).
// Rationale: ~17% of staged lines miss L2 (streaming A through per-XCD 4MB L2),
// so every tile's wait is bounded by the SLOWEST line (L3/HBM latency ~600-1300cy).
// Distance-1 hides only ~1 iteration (~350cy); distance-3 hides ~3 -> compute-bound.
// Per iter: stage(t+3) into buf (t+3)&3, s_waitcnt vmcnt(12) (tile t landed, t+1..t+3
// in flight; tail 8/4/0), raw s_barrier, ds_read buf t&3, 16 MFMA, trailing barrier.
// Hazard: stage(t+3) overwrites the buffer read at t-1; the t-1 trailing barrier
// guarantees all waves consumed those ds_reads (lgkmcnt-drained before their MFMAs,
// which precede the barrier) before any wave can issue the overwrite.
// 64KB LDS -> 2 blocks/CU.
// z==1 (K proj): TRANSPOSED product, writes Kp[bh][key][64] with row-rotation
//                col' = (col + (key&7)*8) & 63 (bank-uniform b128 LDS reads in attn).
// z==2 (V proj): writes Vp[bh][key>>6][d][64] with key' = (key + (d&7)*8) & 63.
template<bool OUT_BF16>
__global__ __launch_bounds__(256) void gemm_bt(
    const __bf16* __restrict__ A,
    const __bf16* __restrict__ W0, const __bf16* __restrict__ W1, const __bf16* __restrict__ W2,
    const float* __restrict__ b0, const float* __restrict__ b1, const float* __restrict__ b2,
    void* out0, void* out1, void* out2, float sc0, float sc1, float sc2) {
  const int z = blockIdx.z;
  const __bf16* W   = (z == 0) ? W0 : (z == 1) ? W1 : W2;
  const float* bias = (z == 0) ? b0 : (z == 1) ? b1 : b2;
  void* out         = (z == 0) ? out0 : (z == 1) ? out1 : out2;
  const float sc    = (z == 0) ? sc0 : (z == 1) ? sc1 : sc2;

  __shared__ __bf16 As[4 * 4096];   // 4 buffers x 128 rows x 32 k
  __shared__ __bf16 Bs[4 * 4096];

  const int tid = threadIdx.x;
  const int w = tid >> 6, l = tid & 63;
  const int quad = l >> 4, l16 = l & 15;
  const int wy = w >> 1, wx = w & 1;
  const int row0 = blockIdx.y * 128;
  const int col0 = blockIdx.x * 128;

  const f32x4 fzero = {0.f, 0.f, 0.f, 0.f};
  f32x4 acc[4][4];
  for (int i = 0; i < 4; i++)
    for (int j = 0; j < 4; j++) acc[i][j] = fzero;

  const int lr = l >> 2;                         // 0..15
  const int sw0 = (((l & 3) ^ (lr & 3)) * 8);    // source k offset (swizzled)
  const int rowA = w * 16 + lr;
  const __bf16* aptr = A + (size_t)(row0 + rowA) * D_MODEL + sw0;
  const __bf16* bptr = W + (size_t)(col0 + rowA) * D_MODEL + sw0;
  const int ldsOff = w * 512 + l * 8;

  const int rswz = (quad ^ (l16 & 3)) * 8;

  // prologue: stage K-steps 0,1,2 into buffers 0,1,2
  #pragma unroll
  for (int p = 0; p < 3; ++p) {
    const int off = p << 12;
    const int kk = p * 32;
    async16(&As[off + ldsOff], aptr + kk);
    async16(&As[off + 2048 + ldsOff], aptr + (size_t)64 * D_MODEL + kk);
    async16(&Bs[off + ldsOff], bptr + kk);
    async16(&Bs[off + 2048 + ldsOff], bptr + (size_t)64 * D_MODEL + kk);
  }

  #pragma unroll 4
  for (int t = 0; t < 32; ++t) {
    const int rb = (t & 3) << 12;
    if (t < 29) {                                // stage t+3, then counted wait for t
      const int sb = ((t + 3) & 3) << 12;
      const int kk = (t + 3) * 32;
      async16(&As[sb + ldsOff], aptr + kk);
      async16(&As[sb + 2048 + ldsOff], aptr + (size_t)64 * D_MODEL + kk);
      async16(&Bs[sb + ldsOff], bptr + kk);
      async16(&Bs[sb + 2048 + ldsOff], bptr + (size_t)64 * D_MODEL + kk);
      asm volatile("s_waitcnt vmcnt(12)" ::: "memory");  // t landed; t+1..t+3 in flight
    } else if (t == 29) {
      asm volatile("s_waitcnt vmcnt(8)" ::: "memory");
    } else if (t == 30) {
      asm volatile("s_waitcnt vmcnt(4)" ::: "memory");
    } else {
      asm volatile("s_waitcnt vmcnt(0)" ::: "memory");
    }
    __builtin_amdgcn_s_barrier();
    bf16x8 af[4], bfr[4];
    #pragma unroll
    for (int mi = 0; mi < 4; mi++) af[mi]  = *(const bf16x8*)&As[rb + (wy * 64 + mi * 16 + l16) * 32 + rswz];
    #pragma unroll
    for (int ni = 0; ni < 4; ni++) bfr[ni] = *(const bf16x8*)&Bs[rb + (wx * 64 + ni * 16 + l16) * 32 + rswz];
    if (z == 1) {
      #pragma unroll
      for (int mi = 0; mi < 4; mi++)
        #pragma unroll
        for (int ni = 0; ni < 4; ni++)
          acc[mi][ni] = mfma16(bfr[ni], af[mi], acc[mi][ni]);   // transposed product
    } else {
      #pragma unroll
      for (int mi = 0; mi < 4; mi++)
        #pragma unroll
        for (int ni = 0; ni < 4; ni++)
          acc[mi][ni] = mfma16(af[mi], bfr[ni], acc[mi][ni]);
    }
    __builtin_amdgcn_s_barrier();
  }

  if (z == 1 && OUT_BF16) {
    // D[wcol][token]: pack 4 hd dims per uint2, rotated within the 64-dim row
    __bf16* kp = (__bf16*)out;
    #pragma unroll
    for (int ni = 0; ni < 4; ni++) {
      const int wcolbase = col0 + wx * 64 + ni * 16 + quad * 4;
      const float4 b4 = *(const float4*)&bias[wcolbase];
      const float bb[4] = {b4.x, b4.y, b4.z, b4.w};
      #pragma unroll
      for (int mi = 0; mi < 4; mi++) {
        const int token = row0 + wy * 64 + mi * 16 + l16;
        const int bh = (token >> 10) * 16 + (wcolbase >> 6);
        const int colp = ((wcolbase & 63) + ((token & 7) << 3)) & 63;   // rotation
        union { __bf16 hh[4]; uint2 uu; } pk;
        #pragma unroll
        for (int r = 0; r < 4; r++) pk.hh[r] = (__bf16)(acc[mi][ni][r] + bb[r]);
        *(uint2*)(kp + ((size_t)bh * SEQ + (token & 1023)) * HD + colp) = pk.uu;
      }
    }
  } else if (z == 2 && OUT_BF16) {
    // chunk-packed Vp[bh][token>>6][d][token'], rotated in key dim
    __bf16* vp = (__bf16*)out;
    #pragma unroll
    for (int ni = 0; ni < 4; ni++) {
      const int col = col0 + wx * 64 + ni * 16 + l16;          // d (model dim)
      const float bv = bias[col];
      #pragma unroll
      for (int mi = 0; mi < 4; mi++) {
        const int token = row0 + wy * 64 + mi * 16 + quad * 4;
        const int bh = (token >> 10) * 16 + (col >> 6);
        const int chk = (token >> 6) & 15;
        const int keyp = ((token & 63) + ((col & 7) << 3)) & 63;        // rotation
        const size_t base = (((size_t)bh * 16 + chk) * 64 + (col & 63)) * 64 + keyp;
        union { __bf16 hh[4]; uint2 uu; } pk;
        #pragma unroll
        for (int r = 0; r < 4; r++) pk.hh[r] = (__bf16)(acc[mi][ni][r] + bv);
        *(uint2*)(vp + base) = pk.uu;
      }
    }
  } else {
    #pragma unroll
    for (int ni = 0; ni < 4; ni++) {
      const int col = col0 + wx * 64 + ni * 16 + l16;
      const float bv = bias[col];
      #pragma unroll
      for (int mi = 0; mi < 4; mi++) {
        const int row = row0 + wy * 64 + mi * 16 + quad * 4;
        #pragma unroll
        for (int r = 0; r < 4; r++) {
          float v = (acc[mi][ni][r] + bv) * sc;
          if (OUT_BF16) ((__bf16*)out)[(size_t)(row + r) * D_MODEL + col] = (__bf16)v;
          else          ((float*)out)[(size_t)(row + r) * D_MODEL + col] = v;
        }
      }
    }
  }
}

// ------------------------------------------------------- attention, DMA-staged (m97-style)
// Block = 4 waves = 64 q-rows of one (bh, group). K+V chunk (16 KB) DMA'd into
// double-buffered LDS via global_load_lds; ONE barrier per chunk (drains the DMA
// issued during the previous chunk's compute -> ~free). All frag reads are
// ds_read_b128, bank-uniform thanks to the global-side row rotation.
// Snake pairing {g, 15-g}: every block runs exactly 17 chunks.
// Causal mask applies ONLY to the diagonal chunk (ch == nch-1): for ch < g,
// kc+63 <= g*64 <= qrow always -> mask hoisted behind a uniform branch.
__global__ __launch_bounds__(256, 2) void attn_kernel(
    const __bf16* __restrict__ Qb, const __bf16* __restrict__ Kp,
    const __bf16* __restrict__ Vp, const float* __restrict__ vimp,
    __bf16* __restrict__ Ob) {
  const int id = blockIdx.x;
  const int bh = id & 63;                 // CU c hosts ids c, c+256 -> same bh: L2 share
  const int gg = id >> 6;                 // 0..7
  const int b = bh >> 4, h = bh & 15;
  const int tid = threadIdx.x;
  const int wave = tid >> 6, lane = tid & 63;
  const int quad = lane >> 4, l16 = lane & 15;

  __shared__ __bf16 Kl[2][4096];          // 64 keys x 64 dims (rotated rows)
  __shared__ __bf16 Vl[2][4096];          // 64 dims x 64 keys (rotated rows)
  __shared__ __bf16 Ps[4][16][72];

  const __bf16* kbase = Kp + (size_t)bh * (SEQ * HD);
  const __bf16* vbase = Vp + (size_t)bh * (SEQ * HD);
  const float* vimpH = vimp + h * SEQ;

  const int rot0 = ((quad + (l16 & 7)) & 7) * 8;        // logical cols quad*8..+7
  const int rot1 = ((quad + 4 + (l16 & 7)) & 7) * 8;    // logical cols 32+quad*8..+7
  const int frow = l16 * 64;

  #pragma unroll 1
  for (int grp = 0; grp < 2; grp++) {
    const int g = grp ? (15 - gg) : gg;
    const int nch = g + 1;
    const int qrow = g * 64 + wave * 16 + l16;
    const __bf16* qp = Qb + (size_t)(b * SEQ + qrow) * D_MODEL + h * HD;
    bf16x8 qa0 = *(const bf16x8*)(qp + quad * 8);        // Q pre-scaled by QSC in gemm
    bf16x8 qa1 = *(const bf16x8*)(qp + 32 + quad * 8);
    float l_i = 0.f;
    f32x4 o[4];
    #pragma unroll
    for (int td = 0; td < 4; td++) { o[td][0] = 0.f; o[td][1] = 0.f; o[td][2] = 0.f; o[td][3] = 0.f; }

    __syncthreads();                      // bufs free of previous group's readers
    async16(&Kl[0][tid * 8], kbase + tid * 8);
    async16(&Kl[0][2048 + tid * 8], kbase + 2048 + tid * 8);
    async16(&Vl[0][tid * 8], vbase + tid * 8);
    async16(&Vl[0][2048 + tid * 8], vbase + 2048 + tid * 8);

    for (int ch = 0; ch < nch; ch++) {
      const int buf = ch & 1;
      __syncthreads();                    // drains DMA for buf (issued ~1 chunk ago)
      if (ch + 1 < nch) {                 // prefetch next chunk into other buffer
        const __bf16* gk = kbase + (ch + 1) * 4096;
        const __bf16* gv = vbase + (ch + 1) * 4096;
        const int nb = buf ^ 1;
        async16(&Kl[nb][tid * 8], gk + tid * 8);
        async16(&Kl[nb][2048 + tid * 8], gk + 2048 + tid * 8);
        async16(&Vl[nb][tid * 8], gv + tid * 8);
        async16(&Vl[nb][2048 + tid * 8], gv + 2048 + tid * 8);
      }
      const int kc = ch * 64;
      float4 vi[4];
      #pragma unroll
      for (int t = 0; t < 4; t++) vi[t] = *(const float4*)(vimpH + kc + t * 16 + quad * 4);
      bf16x8 kf0[4], kf1[4];
      #pragma unroll
      for (int t = 0; t < 4; t++) {
        kf0[t] = *(const bf16x8*)&Kl[buf][t * 1024 + frow + rot0];
        kf1[t] = *(const bf16x8*)&Kl[buf][t * 1024 + frow + rot1];
      }
      bf16x8 vfr0[4], vfr1[4];
      #pragma unroll
      for (int td = 0; td < 4; td++) {
        vfr0[td] = *(const bf16x8*)&Vl[buf][td * 1024 + frow + rot0];
        vfr1[td] = *(const bf16x8*)&Vl[buf][td * 1024 + frow + rot1];
      }
      const f32x4 fz = {0.f, 0.f, 0.f, 0.f};
      float p[4][4];
      float lsum = 0.f;
      if (ch == nch - 1) {                // diagonal chunk: causal mask active
        #pragma unroll
        for (int t = 0; t < 4; t++) {
          f32x4 sacc = fz;
          sacc = mfma16(kf0[t], qa0, sacc);
          sacc = mfma16(kf1[t], qa1, sacc);
          const float vib[4] = {vi[t].x, vi[t].y, vi[t].z, vi[t].w};
          #pragma unroll
          for (int r = 0; r < 4; r++) {
            float pp = exp2f(sacc[r] + BSC * vib[r]);
            pp = (kc + t * 16 + quad * 4 + r <= qrow) ? pp : 0.f;
            p[t][r] = pp;
            lsum += pp;
          }
        }
      } else {                            // interior chunk: all keys <= qrow
        #pragma unroll
        for (int t = 0; t < 4; t++) {
          f32x4 sacc = fz;
          sacc = mfma16(kf0[t], qa0, sacc);
          sacc = mfma16(kf1[t], qa1, sacc);
          const float vib[4] = {vi[t].x, vi[t].y, vi[t].z, vi[t].w};
          #pragma unroll
          for (int r = 0; r < 4; r++) {
            float pp = exp2f(sacc[r] + BSC * vib[r]);
            p[t][r] = pp;
            lsum += pp;
          }
        }
      }
      l_i += lsum;
      #pragma unroll
      for (int t = 0; t < 4; t++) {
        union { __bf16 hh[4]; uint2 uu; } pk;
        #pragma unroll
        for (int r = 0; r < 4; r++) pk.hh[r] = (__bf16)p[t][r];
        *(uint2*)&Ps[wave][l16][t * 16 + quad * 4] = pk.uu;
      }
      bf16x8 pf0 = *(const bf16x8*)&Ps[wave][l16][quad * 8];
      bf16x8 pf1 = *(const bf16x8*)&Ps[wave][l16][32 + quad * 8];
      #pragma unroll
      for (int td = 0; td < 4; td++) {
        o[td] = mfma16(vfr0[td], pf0, o[td]);
        o[td] = mfma16(vfr1[td], pf1, o[td]);
      }
    }

    float L = l_i;
    L += __shfl_xor(L, 16);
    L += __shfl_xor(L, 32);
    const float il = 1.0f / L;
    __bf16* op = Ob + (size_t)(b * SEQ + qrow) * D_MODEL + h * HD;
    #pragma unroll
    for (int td = 0; td < 4; td++) {
      union { __bf16 hh[4]; uint2 uu; } pk;
      #pragma unroll
      for (int r = 0; r < 4; r++) pk.hh[r] = (__bf16)(o[td][r] * il);
      *(uint2*)(op + td * 16 + quad * 4) = pk.uu;
    }
  }
}

// ---------------------------------------------------------------------------
extern "C" void kernel_launch(void* const* d_in, const int* in_sizes, int n_in,
                              void* d_out, int out_size, void* d_ws, size_t ws_size,
                              hipStream_t stream) {
  const float* x     = (const float*)d_in[0];
  const float* Wq    = (const float*)d_in[1];
  const float* bq    = (const float*)d_in[2];
  const float* Wk    = (const float*)d_in[3];
  const float* bk    = (const float*)d_in[4];
  const float* Wv    = (const float*)d_in[5];
  const float* bv    = (const float*)d_in[6];
  const float* Wo    = (const float*)d_in[7];
  const float* bo    = (const float*)d_in[8];
  const float* Wimp  = (const float*)d_in[9];
  const float* bimp  = (const float*)d_in[10];
  // d_in[11] = k_ema (unused: kimp bias is per-q-row constant, cancels in softmax)
  const float* v_ema = (const float*)d_in[12];
  float* out = (float*)d_out;

  char* ws = (char*)d_ws;
  __bf16* x_bf  = (__bf16*)(ws);                        // 8 MB
  __bf16* wq_bf = (__bf16*)(ws + (8ull  << 20));        // 2 MB each
  __bf16* wk_bf = (__bf16*)(ws + (10ull << 20));
  __bf16* wv_bf = (__bf16*)(ws + (12ull << 20));
  __bf16* wo_bf = (__bf16*)(ws + (14ull << 20));
  __bf16* q_bf  = (__bf16*)(ws + (16ull << 20));        // 8 MB each
  __bf16* kp_bf = (__bf16*)(ws + (24ull << 20));        // K packed+rotated [bh][key][64]
  __bf16* vp_bf = (__bf16*)(ws + (32ull << 20));        // V packed+rotated [bh][ch][d][64]
  __bf16* a_bf  = (__bf16*)(ws + (40ull << 20));
  float*  vimp  = (float*)(ws + (48ull << 20));         // 64 KB

  prep_kernel<<<8448, 256, 0, stream>>>(
      x, Wq, Wk, Wv, Wo, v_ema, Wimp, bimp,
      x_bf, wq_bf, wk_bf, wv_bf, wo_bf, vimp);

  // Q,K,V projections; Q pre-scaled by 0.125*log2(e); K,V written per-head packed+rotated
  gemm_bt<true><<<dim3(8, 32, 3), 256, 0, stream>>>(
      x_bf, wq_bf, wk_bf, wv_bf, bq, bk, bv,
      (void*)q_bf, (void*)kp_bf, (void*)vp_bf, QSC, 1.0f, 1.0f);

  attn_kernel<<<dim3(512), 256, 0, stream>>>(
      q_bf, kp_bf, vp_bf, vimp, a_bf);

  gemm_bt<false><<<dim3(8, 32, 1), 256, 0, stream>>>(
      a_bf, wo_bf, wo_bf, wo_bf, bo, bo, bo,
      (void*)out, (void*)out, (void*)out, 1.0f, 1.0f, 1.0f);
}